// Round 2
// baseline (602.396 us; speedup 1.0000x reference)
//
#include <hip/hip_runtime.h>

typedef unsigned short u16;
typedef __bf16 bf16_t;
typedef bf16_t bf16x8 __attribute__((ext_vector_type(8)));
typedef float floatx4 __attribute__((ext_vector_type(4)));

__device__ __forceinline__ float bf2f(u16 h) {
    union { unsigned u; float f; } v;
    v.u = ((unsigned)h) << 16;
    return v.f;
}

__device__ __forceinline__ u16 f2bf(float f) {
    union { float f; unsigned u; } v;
    v.f = f;
    unsigned r = v.u + 0x7fffu + ((v.u >> 16) & 1u);
    return (u16)(r >> 16);
}

// ---------------------------------------------------------------------------
// Weight transposes: fp32 in -> bf16 transposed out (tiny, L2-resident)
// ---------------------------------------------------------------------------
__global__ void transpose_one(const float* __restrict__ W, u16* __restrict__ Wt,
                              int K, int N) {
    int idx = blockIdx.x * 256 + threadIdx.x;
    if (idx >= K * N) return;
    int nrow = idx / K;
    int k = idx - nrow * K;
    Wt[idx] = f2bf(W[k * N + nrow]);   // Wt[n][k] = W[k][n]
}

// WkvT [1024][768]: rows 0..511 = Wk^T, rows 512..1023 = Wv^T
__global__ void transpose_kv(const float* __restrict__ Wk, const float* __restrict__ Wv,
                             u16* __restrict__ Wt) {
    int idx = blockIdx.x * 256 + threadIdx.x;
    if (idx >= 1024 * 768) return;
    int nrow = idx / 768;
    int k = idx - nrow * 768;
    Wt[idx] = f2bf((nrow < 512) ? Wk[k * 512 + nrow] : Wv[k * 512 + (nrow - 512)]);
}

// ---------------------------------------------------------------------------
// GEMM: C[M,N] = A[M,K] * Bt[N,K]^T (+bias), bf16 MFMA, fp32 accum.
// A may be fp32 (converted during staging) or bf16. C may be fp32 or bf16.
// 128x128 tile, BK=32, 256 threads = 4 waves in 2x2, each wave 64x64 (4x4 MFMA)
// ---------------------------------------------------------------------------
#define TM 128
#define TN 128
#define TK 32
#define LK 40   // LDS row stride (+8 pad: 80B rows -> 2-way bank aliasing = free)

template <bool A_F32, bool OUT_F32>
__global__ __launch_bounds__(256) void gemm_bt(
    const void* __restrict__ A_, const u16* __restrict__ Bt,
    void* __restrict__ C_, const float* __restrict__ bias,
    int M, int K, int N)
{
    __shared__ u16 As[TM * LK];
    __shared__ u16 Bs[TN * LK];

    const int tid  = threadIdx.x;
    const int lane = tid & 63;
    const int wave = tid >> 6;
    const int quad = lane >> 4;
    const int l16  = lane & 15;
    const int wm   = (wave & 1) * 64;
    const int wn   = (wave >> 1) * 64;
    const long bm  = (long)blockIdx.x * TM;
    const long bn  = (long)blockIdx.y * TN;

    const float* Af = (const float*)A_;
    const u16*   Ab = (const u16*)A_;

    floatx4 acc[4][4] = {};

    for (int k0 = 0; k0 < K; k0 += TK) {
        // stage A,B tiles: 128x32 bf16 each = 512 x 16B vectors -> 2/thread
        #pragma unroll
        for (int p = 0; p < 2; ++p) {
            int v = tid + p * 256;
            int r = v >> 2;
            int c = (v & 3) * 8;
            long gr = bm + r;
            uint4 av;
            if (A_F32) {
                float4 f0 = make_float4(0.f, 0.f, 0.f, 0.f);
                float4 f1 = make_float4(0.f, 0.f, 0.f, 0.f);
                if (gr < M) {
                    f0 = *(const float4*)(Af + gr * K + k0 + c);
                    f1 = *(const float4*)(Af + gr * K + k0 + c + 4);
                }
                union { u16 h[8]; uint4 u; } pk;
                pk.h[0] = f2bf(f0.x); pk.h[1] = f2bf(f0.y);
                pk.h[2] = f2bf(f0.z); pk.h[3] = f2bf(f0.w);
                pk.h[4] = f2bf(f1.x); pk.h[5] = f2bf(f1.y);
                pk.h[6] = f2bf(f1.z); pk.h[7] = f2bf(f1.w);
                av = pk.u;
            } else {
                av = make_uint4(0, 0, 0, 0);
                if (gr < M) av = *(const uint4*)(Ab + gr * K + k0 + c);
            }
            *(uint4*)(&As[r * LK + c]) = av;
            uint4 bv = *(const uint4*)(Bt + (bn + r) * K + k0 + c);
            *(uint4*)(&Bs[r * LK + c]) = bv;
        }
        __syncthreads();

        bf16x8 af[4], bfr[4];
        #pragma unroll
        for (int i = 0; i < 4; ++i)
            af[i] = *(const bf16x8*)(&As[(wm + i * 16 + l16) * LK + quad * 8]);
        #pragma unroll
        for (int j = 0; j < 4; ++j)
            bfr[j] = *(const bf16x8*)(&Bs[(wn + j * 16 + l16) * LK + quad * 8]);
        #pragma unroll
        for (int i = 0; i < 4; ++i)
            #pragma unroll
            for (int j = 0; j < 4; ++j)
                acc[i][j] = __builtin_amdgcn_mfma_f32_16x16x32_bf16(
                    af[i], bfr[j], acc[i][j], 0, 0, 0);
        __syncthreads();
    }

    // epilogue: D row = quad*4 + reg, col = l16  (verified m89/m91 layout)
    #pragma unroll
    for (int i = 0; i < 4; ++i) {
        #pragma unroll
        for (int r = 0; r < 4; ++r) {
            long row = bm + wm + i * 16 + quad * 4 + r;
            if (row >= M) continue;
            #pragma unroll
            for (int j = 0; j < 4; ++j) {
                long col = bn + wn + j * 16 + l16;
                float val = acc[i][j][r];
                if (bias) val += bias[col];
                if (OUT_F32) ((float*)C_)[row * N + col] = val;
                else         ((u16*)C_)[row * N + col] = f2bf(val);
            }
        }
    }
}

// ---------------------------------------------------------------------------
// Fused attention per (64-q-tile, h, n). bf16 in/out (workspace). In-place:
// each block reads exactly the [n, q0:q0+64, h*64:h*64+64] slice it writes.
// ---------------------------------------------------------------------------
__global__ __launch_bounds__(256) void attn_kernel(
    const u16* __restrict__ qb,   // [N, 4096, 512] bf16
    const u16* __restrict__ kvb,  // [N*77, 1024] bf16 (cols 0..511 = k, 512.. = v)
    u16* __restrict__ ob)         // [N, 4096, 512] bf16
{
    const int QL = 4096, HS = 512;
    const int q0 = blockIdx.x * 64;
    const int h  = blockIdx.y;
    const int n  = blockIdx.z;

    __shared__ u16  qs[64 * 72];    // q tile [q][s], pad 64->72
    __shared__ u16  ks[80 * 72];    // k [c][s], c padded to 80 (zeros)
    __shared__ u16  vts[64 * 104];  // v^T [s][c], c padded to 96, stride 104
    __shared__ float sc[64 * 84];   // scores fp32 [q][c], stride 84
    __shared__ u16  wsm[64 * 104];  // softmax weights bf16 [q][c], stride 104

    const int tid  = threadIdx.x;
    const int lane = tid & 63;
    const int wave = tid >> 6;
    const int quad = lane >> 4;
    const int l16  = lane & 15;

    // stage q tile: 64 rows x 64 cols = 512 x 16B
    const u16* qbase = qb + ((long)n * QL + q0) * HS + h * 64;
    #pragma unroll
    for (int p = 0; p < 2; ++p) {
        int v = tid + p * 256;
        int r = v >> 3, g = (v & 7) * 8;
        *(uint4*)(&qs[r * 72 + g]) = *(const uint4*)(qbase + (long)r * HS + g);
    }
    // stage k rows (zero-pad c>=77)
    const u16* kbase = kvb + (long)n * 77 * 1024 + h * 64;
    for (int v = tid; v < 640; v += 256) {
        int c = v >> 3, g = (v & 7) * 8;
        uint4 val = make_uint4(0, 0, 0, 0);
        if (c < 77) val = *(const uint4*)(kbase + (long)c * 1024 + g);
        *(uint4*)(&ks[c * 72 + g]) = val;
    }
    // stage v transposed: vts[s][c] = v[c][s]
    const u16* vbase = kvb + (long)n * 77 * 1024 + 512 + h * 64;
    for (int e = tid; e < 64 * 96; e += 256) {
        int s = e / 96, c = e - s * 96;
        u16 val = 0;
        if (c < 77) val = vbase[(long)c * 1024 + s];
        vts[s * 104 + c] = val;
    }
    __syncthreads();

    // scores 64x80 = q(64x64) . k^T ; wave w handles q-rows w*16..w*16+15
    floatx4 accS[5] = {};
    #pragma unroll
    for (int kk = 0; kk < 2; ++kk) {
        bf16x8 aq = *(const bf16x8*)(&qs[(wave * 16 + l16) * 72 + kk * 32 + quad * 8]);
        #pragma unroll
        for (int j = 0; j < 5; ++j) {
            bf16x8 bk = *(const bf16x8*)(&ks[(j * 16 + l16) * 72 + kk * 32 + quad * 8]);
            accS[j] = __builtin_amdgcn_mfma_f32_16x16x32_bf16(aq, bk, accS[j], 0, 0, 0);
        }
    }
    #pragma unroll
    for (int j = 0; j < 5; ++j)
        #pragma unroll
        for (int r = 0; r < 4; ++r)
            sc[(wave * 16 + quad * 4 + r) * 84 + j * 16 + l16] = accS[j][r] * 0.125f;
    __syncthreads();

    // softmax over c<77, 4 threads per row
    {
        int row = tid >> 2, part = tid & 3;
        float mx = -1e30f;
        for (int c = part; c < 77; c += 4) mx = fmaxf(mx, sc[row * 84 + c]);
        mx = fmaxf(mx, __shfl_xor(mx, 1, 4));
        mx = fmaxf(mx, __shfl_xor(mx, 2, 4));
        float sum = 0.f;
        for (int c = part; c < 77; c += 4) {
            float e = __expf(sc[row * 84 + c] - mx);
            sc[row * 84 + c] = e;
            sum += e;
        }
        sum += __shfl_xor(sum, 1, 4);
        sum += __shfl_xor(sum, 2, 4);
        float inv = 1.f / sum;
        for (int c = part; c < 96; c += 4) {
            float w = (c < 77) ? sc[row * 84 + c] * inv : 0.f;
            wsm[row * 104 + c] = f2bf(w);
        }
    }
    __syncthreads();

    // out 64x64 = w(64x96) . v(96x64); wave w handles q-rows w*16..
    floatx4 accO[4] = {};
    #pragma unroll
    for (int kk = 0; kk < 3; ++kk) {
        bf16x8 aw = *(const bf16x8*)(&wsm[(wave * 16 + l16) * 104 + kk * 32 + quad * 8]);
        #pragma unroll
        for (int j = 0; j < 4; ++j) {
            bf16x8 bv = *(const bf16x8*)(&vts[(j * 16 + l16) * 104 + kk * 32 + quad * 8]);
            accO[j] = __builtin_amdgcn_mfma_f32_16x16x32_bf16(aw, bv, accO[j], 0, 0, 0);
        }
    }
    u16* obase = ob + ((long)n * QL + q0) * HS + h * 64;
    #pragma unroll
    for (int j = 0; j < 4; ++j)
        #pragma unroll
        for (int r = 0; r < 4; ++r) {
            int qr = wave * 16 + quad * 4 + r;
            obase[(long)qr * HS + j * 16 + l16] = f2bf(accO[j][r]);
        }
}

// ---------------------------------------------------------------------------
extern "C" void kernel_launch(void* const* d_in, const int* in_sizes, int n_in,
                              void* d_out, int out_size, void* d_ws, size_t ws_size,
                              hipStream_t stream) {
    const float* query   = (const float*)d_in[0];  // [16,4096,512] fp32
    const float* context = (const float*)d_in[1];  // [16,77,768]   fp32
    const float* Wq      = (const float*)d_in[2];  // [512,512]     fp32
    const float* Wk      = (const float*)d_in[3];  // [768,512]     fp32
    const float* Wv      = (const float*)d_in[4];  // [768,512]     fp32
    const float* Wo      = (const float*)d_in[5];  // [512,512]     fp32
    const float* bo      = (const float*)d_in[6];  // [512]         fp32
    float* out = (float*)d_out;                    // [16,4096,512] fp32

    // workspace layout (u16 elements) — total ~72.3 MB
    u16* q_ws  = (u16*)d_ws;            // 16*4096*512 = 33,554,432 (also attn out, in-place)
    u16* kv_ws = q_ws + 33554432;       // 1232*1024 = 1,261,568
    u16* WqT   = kv_ws + 1261568;       // 512*512
    u16* WkvT  = WqT + 262144;          // 1024*768
    u16* WoT   = WkvT + 786432;         // 512*512

    transpose_one<<<(512 * 512 + 255) / 256, 256, 0, stream>>>(Wq, WqT, 512, 512);
    transpose_kv<<<(1024 * 768 + 255) / 256, 256, 0, stream>>>(Wk, Wv, WkvT);
    transpose_one<<<(512 * 512 + 255) / 256, 256, 0, stream>>>(Wo, WoT, 512, 512);

    // q projection: [65536,512](fp32) x [512,512] -> bf16 ws
    gemm_bt<true, false><<<dim3(512, 4), 256, 0, stream>>>(
        (const void*)query, WqT, (void*)q_ws, nullptr, 65536, 512, 512);
    // k,v projection fused: [1232,768](fp32) x [768,1024] -> bf16 ws
    gemm_bt<true, false><<<dim3(10, 8), 256, 0, stream>>>(
        (const void*)context, WkvT, (void*)kv_ws, nullptr, 1232, 768, 1024);
    // attention, in-place on q_ws (bf16)
    attn_kernel<<<dim3(64, 8, 16), 256, 0, stream>>>(q_ws, kv_ws, q_ws);
    // output projection + fp32 bias: [65536,512](bf16) x [512,512] -> fp32 out
    gemm_bt<false, true><<<dim3(512, 4), 256, 0, stream>>>(
        (const void*)q_ws, WoT, (void*)out, bo, 65536, 512, 512);
}

// Round 3
// 482.423 us; speedup vs baseline: 1.2487x; 1.2487x over previous
//
#include <hip/hip_runtime.h>

typedef unsigned short u16;
typedef __bf16 bf16_t;
typedef bf16_t bf16x8 __attribute__((ext_vector_type(8)));
typedef float floatx4 __attribute__((ext_vector_type(4)));

__device__ __forceinline__ float bf2f(u16 h) {
    union { unsigned u; float f; } v;
    v.u = ((unsigned)h) << 16;
    return v.f;
}

__device__ __forceinline__ u16 f2bf(float f) {
    union { float f; unsigned u; } v;
    v.f = f;
    unsigned r = v.u + 0x7fffu + ((v.u >> 16) & 1u);
    return (u16)(r >> 16);
}

// ---------------------------------------------------------------------------
// Weight transposes: fp32 in -> bf16 transposed out (tiny, L2-resident)
// ---------------------------------------------------------------------------
__global__ void transpose_one(const float* __restrict__ W, u16* __restrict__ Wt,
                              int K, int N) {
    int idx = blockIdx.x * 256 + threadIdx.x;
    if (idx >= K * N) return;
    int nrow = idx / K;
    int k = idx - nrow * K;
    Wt[idx] = f2bf(W[k * N + nrow]);   // Wt[n][k] = W[k][n]
}

// WkvT [1024][768]: rows 0..511 = Wk^T, rows 512..1023 = Wv^T
__global__ void transpose_kv(const float* __restrict__ Wk, const float* __restrict__ Wv,
                             u16* __restrict__ Wt) {
    int idx = blockIdx.x * 256 + threadIdx.x;
    if (idx >= 1024 * 768) return;
    int nrow = idx / 768;
    int k = idx - nrow * 768;
    Wt[idx] = f2bf((nrow < 512) ? Wk[k * 512 + nrow] : Wv[k * 512 + (nrow - 512)]);
}

// ---------------------------------------------------------------------------
// GEMM: C[M,N] = A[M,K] * Bt[N,K]^T (+bias), bf16 MFMA, fp32 accum.
// (unchanged from round-2 passing version)
// ---------------------------------------------------------------------------
#define TM 128
#define TN 128
#define TK 32
#define LK 40

template <bool A_F32, bool OUT_F32>
__global__ __launch_bounds__(256) void gemm_bt(
    const void* __restrict__ A_, const u16* __restrict__ Bt,
    void* __restrict__ C_, const float* __restrict__ bias,
    int M, int K, int N)
{
    __shared__ u16 As[TM * LK];
    __shared__ u16 Bs[TN * LK];

    const int tid  = threadIdx.x;
    const int lane = tid & 63;
    const int wave = tid >> 6;
    const int quad = lane >> 4;
    const int l16  = lane & 15;
    const int wm   = (wave & 1) * 64;
    const int wn   = (wave >> 1) * 64;
    const long bm  = (long)blockIdx.x * TM;
    const long bn  = (long)blockIdx.y * TN;

    const float* Af = (const float*)A_;
    const u16*   Ab = (const u16*)A_;

    floatx4 acc[4][4] = {};

    for (int k0 = 0; k0 < K; k0 += TK) {
        #pragma unroll
        for (int p = 0; p < 2; ++p) {
            int v = tid + p * 256;
            int r = v >> 2;
            int c = (v & 3) * 8;
            long gr = bm + r;
            uint4 av;
            if (A_F32) {
                float4 f0 = make_float4(0.f, 0.f, 0.f, 0.f);
                float4 f1 = make_float4(0.f, 0.f, 0.f, 0.f);
                if (gr < M) {
                    f0 = *(const float4*)(Af + gr * K + k0 + c);
                    f1 = *(const float4*)(Af + gr * K + k0 + c + 4);
                }
                union { u16 h[8]; uint4 u; } pk;
                pk.h[0] = f2bf(f0.x); pk.h[1] = f2bf(f0.y);
                pk.h[2] = f2bf(f0.z); pk.h[3] = f2bf(f0.w);
                pk.h[4] = f2bf(f1.x); pk.h[5] = f2bf(f1.y);
                pk.h[6] = f2bf(f1.z); pk.h[7] = f2bf(f1.w);
                av = pk.u;
            } else {
                av = make_uint4(0, 0, 0, 0);
                if (gr < M) av = *(const uint4*)(Ab + gr * K + k0 + c);
            }
            *(uint4*)(&As[r * LK + c]) = av;
            uint4 bv = *(const uint4*)(Bt + (bn + r) * K + k0 + c);
            *(uint4*)(&Bs[r * LK + c]) = bv;
        }
        __syncthreads();

        bf16x8 af[4], bfr[4];
        #pragma unroll
        for (int i = 0; i < 4; ++i)
            af[i] = *(const bf16x8*)(&As[(wm + i * 16 + l16) * LK + quad * 8]);
        #pragma unroll
        for (int j = 0; j < 4; ++j)
            bfr[j] = *(const bf16x8*)(&Bs[(wn + j * 16 + l16) * LK + quad * 8]);
        #pragma unroll
        for (int i = 0; i < 4; ++i)
            #pragma unroll
            for (int j = 0; j < 4; ++j)
                acc[i][j] = __builtin_amdgcn_mfma_f32_16x16x32_bf16(
                    af[i], bfr[j], acc[i][j], 0, 0, 0);
        __syncthreads();
    }

    #pragma unroll
    for (int i = 0; i < 4; ++i) {
        #pragma unroll
        for (int r = 0; r < 4; ++r) {
            long row = bm + wm + i * 16 + quad * 4 + r;
            if (row >= M) continue;
            #pragma unroll
            for (int j = 0; j < 4; ++j) {
                long col = bn + wn + j * 16 + l16;
                float val = acc[i][j][r];
                if (bias) val += bias[col];
                if (OUT_F32) ((float*)C_)[row * N + col] = val;
                else         ((u16*)C_)[row * N + col] = f2bf(val);
            }
        }
    }
}

// ---------------------------------------------------------------------------
// Fused attention v2. Grid (qc=16, h=8, n=16); block = 256 q-rows of one
// (n,h), processed as 2 tiles of 128. k/v staged ONCE per block; V^T built by
// coalesced load + LDS->LDS transpose; softmax entirely in registers via
// __shfl_xor; q-tile and P share one LDS buffer. In-place safe (block reads
// exactly the q slice it writes).
// ---------------------------------------------------------------------------
__global__ __launch_bounds__(256) void attn_kernel(
    const u16* __restrict__ qb,   // [N, 4096, 512] bf16
    const u16* __restrict__ kvb,  // [N*77, 1024] bf16 (cols 0..511 k, 512.. v)
    u16* __restrict__ ob)         // [N, 4096, 512] bf16
{
    const int QL = 4096, HS = 512;
    const int q0 = blockIdx.x * 256;
    const int h  = blockIdx.y;
    const int n  = blockIdx.z;

    __shared__ u16 sQP[128 * 104];  // q tile (stride 72) / P (stride 104): 26.6 KB
    __shared__ u16 ks [80 * 72];    // k [c][s], c zero-padded to 80: 11.5 KB
    __shared__ u16 vts[64 * 104];   // V^T [s][c], c zero-padded to 96: 13.3 KB

    const int tid  = threadIdx.x;
    const int lane = tid & 63;
    const int wave = tid >> 6;
    const int quad = lane >> 4;
    const int l16  = lane & 15;
    const int wm   = wave * 32;     // wave's q-row offset within 128-tile

    // ---- stage k rows (coalesced, zero-pad c>=77) ----
    const u16* kbase = kvb + (long)n * 77 * 1024 + h * 64;
    for (int v = tid; v < 640; v += 256) {
        int c = v >> 3, g = (v & 7) * 8;
        uint4 val = make_uint4(0, 0, 0, 0);
        if (c < 77) val = *(const uint4*)(kbase + (long)c * 1024 + g);
        *(uint4*)(&ks[c * 72 + g]) = val;
    }
    // ---- stage v rows coalesced into sQP scratch [c][s] stride 64 ----
    const u16* vbase = kvb + (long)n * 77 * 1024 + 512 + h * 64;
    for (int v = tid; v < 616; v += 256) {          // 77 rows x 8 uint4
        int c = v >> 3, g = (v & 7) * 8;
        *(uint4*)(&sQP[c * 64 + g]) = *(const uint4*)(vbase + (long)c * 1024 + g);
    }
    __syncthreads();
    // ---- LDS->LDS transpose into vts[s][c] (zero c>=77) ----
    for (int e = tid; e < 64 * 96; e += 256) {
        int c = e >> 6, s = e & 63;                 // lanes: s fastest (reads conflict-free)
        u16 val = (c < 77) ? sQP[c * 64 + s] : (u16)0;
        vts[s * 104 + c] = val;
    }
    __syncthreads();

    const bool v4ok = (l16 < 13);   // j=4 -> c = 64+l16, valid iff c<77

    for (int it = 0; it < 2; ++it) {
        const long qrow0 = (long)q0 + it * 128;
        const u16* qbase = qb + ((long)n * QL + qrow0) * HS + h * 64;
        u16*       obase = ob + ((long)n * QL + qrow0) * HS + h * 64;

        // ---- stage q tile 128x64 (stride 72) ----
        #pragma unroll
        for (int p = 0; p < 4; ++p) {
            int v = tid + p * 256;
            int r = v >> 3, g = (v & 7) * 8;
            *(uint4*)(&sQP[r * 72 + g]) = *(const uint4*)(qbase + (long)r * HS + g);
        }
        __syncthreads();

        // ---- QK^T: wave covers rows wm..wm+31 (2 row-tiles x 5 col-tiles) ----
        floatx4 accS[2][5] = {};
        #pragma unroll
        for (int kk = 0; kk < 2; ++kk) {
            bf16x8 aq[2], bk[5];
            #pragma unroll
            for (int t = 0; t < 2; ++t)
                aq[t] = *(const bf16x8*)(&sQP[(wm + t * 16 + l16) * 72 + kk * 32 + quad * 8]);
            #pragma unroll
            for (int j = 0; j < 5; ++j)
                bk[j] = *(const bf16x8*)(&ks[(j * 16 + l16) * 72 + kk * 32 + quad * 8]);
            #pragma unroll
            for (int t = 0; t < 2; ++t)
                #pragma unroll
                for (int j = 0; j < 5; ++j)
                    accS[t][j] = __builtin_amdgcn_mfma_f32_16x16x32_bf16(
                        aq[t], bk[j], accS[t][j], 0, 0, 0);
        }

        // ---- softmax in registers (row's 80 cols live in 5 regs x 16 lanes) ----
        float pw[2][5][4];
        #pragma unroll
        for (int t = 0; t < 2; ++t) {
            #pragma unroll
            for (int r = 0; r < 4; ++r) {
                float v0 = accS[t][0][r] * 0.125f;
                float v1 = accS[t][1][r] * 0.125f;
                float v2 = accS[t][2][r] * 0.125f;
                float v3 = accS[t][3][r] * 0.125f;
                float v4 = v4ok ? accS[t][4][r] * 0.125f : -1e30f;
                float mx = fmaxf(fmaxf(fmaxf(v0, v1), fmaxf(v2, v3)), v4);
                mx = fmaxf(mx, __shfl_xor(mx, 1));
                mx = fmaxf(mx, __shfl_xor(mx, 2));
                mx = fmaxf(mx, __shfl_xor(mx, 4));
                mx = fmaxf(mx, __shfl_xor(mx, 8));
                float e0 = __expf(v0 - mx), e1 = __expf(v1 - mx);
                float e2 = __expf(v2 - mx), e3 = __expf(v3 - mx);
                float e4 = __expf(v4 - mx);
                float sum = e0 + e1 + e2 + e3 + e4;
                sum += __shfl_xor(sum, 1);
                sum += __shfl_xor(sum, 2);
                sum += __shfl_xor(sum, 4);
                sum += __shfl_xor(sum, 8);
                float inv = 1.f / sum;
                pw[t][0][r] = e0 * inv; pw[t][1][r] = e1 * inv;
                pw[t][2][r] = e2 * inv; pw[t][3][r] = e3 * inv;
                pw[t][4][r] = e4 * inv;
            }
        }
        __syncthreads();   // all QK^T reads of sQP done -> safe to overwrite with P

        // ---- write P (bf16) into sQP [row][c] stride 104; zero cols 80..95 ----
        #pragma unroll
        for (int t = 0; t < 2; ++t) {
            #pragma unroll
            for (int r = 0; r < 4; ++r) {
                int row = wm + t * 16 + quad * 4 + r;
                #pragma unroll
                for (int j = 0; j < 5; ++j)
                    sQP[row * 104 + j * 16 + l16] = f2bf(pw[t][j][r]);
                sQP[row * 104 + 80 + l16] = 0;
            }
        }
        __syncthreads();

        // ---- PV: out[128,64] = P[128,96] @ V[96,64] ----
        floatx4 accO[2][4] = {};
        #pragma unroll
        for (int kk = 0; kk < 3; ++kk) {
            bf16x8 aw[2], bv[4];
            #pragma unroll
            for (int t = 0; t < 2; ++t)
                aw[t] = *(const bf16x8*)(&sQP[(wm + t * 16 + l16) * 104 + kk * 32 + quad * 8]);
            #pragma unroll
            for (int j = 0; j < 4; ++j)
                bv[j] = *(const bf16x8*)(&vts[(j * 16 + l16) * 104 + kk * 32 + quad * 8]);
            #pragma unroll
            for (int t = 0; t < 2; ++t)
                #pragma unroll
                for (int j = 0; j < 4; ++j)
                    accO[t][j] = __builtin_amdgcn_mfma_f32_16x16x32_bf16(
                        aw[t], bv[j], accO[t][j], 0, 0, 0);
        }

        // ---- store out tile ----
        #pragma unroll
        for (int t = 0; t < 2; ++t)
            #pragma unroll
            for (int j = 0; j < 4; ++j)
                #pragma unroll
                for (int r = 0; r < 4; ++r) {
                    int row = wm + t * 16 + quad * 4 + r;
                    obase[(long)row * HS + j * 16 + l16] = f2bf(accO[t][j][r]);
                }
        __syncthreads();   // protect sQP before next iteration's q staging
    }
}

// ---------------------------------------------------------------------------
extern "C" void kernel_launch(void* const* d_in, const int* in_sizes, int n_in,
                              void* d_out, int out_size, void* d_ws, size_t ws_size,
                              hipStream_t stream) {
    const float* query   = (const float*)d_in[0];  // [16,4096,512] fp32
    const float* context = (const float*)d_in[1];  // [16,77,768]   fp32
    const float* Wq      = (const float*)d_in[2];  // [512,512]     fp32
    const float* Wk      = (const float*)d_in[3];  // [768,512]     fp32
    const float* Wv      = (const float*)d_in[4];  // [768,512]     fp32
    const float* Wo      = (const float*)d_in[5];  // [512,512]     fp32
    const float* bo      = (const float*)d_in[6];  // [512]         fp32
    float* out = (float*)d_out;                    // [16,4096,512] fp32

    // workspace layout (u16 elements) — total ~72.3 MB
    u16* q_ws  = (u16*)d_ws;            // 16*4096*512 (also attn out, in-place)
    u16* kv_ws = q_ws + 33554432;       // 1232*1024
    u16* WqT   = kv_ws + 1261568;       // 512*512
    u16* WkvT  = WqT + 262144;          // 1024*768
    u16* WoT   = WkvT + 786432;         // 512*512

    transpose_one<<<(512 * 512 + 255) / 256, 256, 0, stream>>>(Wq, WqT, 512, 512);
    transpose_kv<<<(1024 * 768 + 255) / 256, 256, 0, stream>>>(Wk, Wv, WkvT);
    transpose_one<<<(512 * 512 + 255) / 256, 256, 0, stream>>>(Wo, WoT, 512, 512);

    // q projection: [65536,512](fp32) x [512,512] -> bf16 ws
    gemm_bt<true, false><<<dim3(512, 4), 256, 0, stream>>>(
        (const void*)query, WqT, (void*)q_ws, nullptr, 65536, 512, 512);
    // k,v projection fused: [1232,768](fp32) x [768,1024] -> bf16 ws
    gemm_bt<true, false><<<dim3(10, 8), 256, 0, stream>>>(
        (const void*)context, WkvT, (void*)kv_ws, nullptr, 1232, 768, 1024);
    // attention, in-place on q_ws (bf16)
    attn_kernel<<<dim3(16, 8, 16), 256, 0, stream>>>(q_ws, kv_ws, q_ws);
    // output projection + fp32 bias: [65536,512](bf16) x [512,512] -> fp32 out
    gemm_bt<false, true><<<dim3(512, 4), 256, 0, stream>>>(
        (const void*)q_ws, WoT, (void*)out, bo, 65536, 512, 512);
}